// Round 1
// baseline (344.900 us; speedup 1.0000x reference)
//
#include <hip/hip_runtime.h>
#include <hip/hip_bf16.h>

// Sizes
#define NB   8
#define CIN  128
#define HH_  64
#define WW_  64
#define COUT 128
#define MIDC 16
#define EPSV 1e-5f

// workspace layout
#define XTP_ELEMS (8*68*68*128)            // padded channels-last x, bf16
#define XTP_BYTES ((size_t)XTP_ELEMS*2)    // 9,469,952
#define WB2_ELEMS (2*36*1024*32)           // repacked weights, bf16
#define WB2_BYTES ((size_t)WB2_ELEMS*2)    // 4,718,592
#define STATS_OFF (XTP_BYTES + WB2_BYTES)  // 128 float2

typedef __attribute__((ext_vector_type(8))) short short8;
typedef __attribute__((ext_vector_type(4))) float f32x4;

__device__ __forceinline__ void gload_lds16(const void* g, void* l) {
    __builtin_amdgcn_global_load_lds(
        (const __attribute__((address_space(1))) void*)g,
        (__attribute__((address_space(3))) void*)l, 16, 0, 0);
}

// ---------------------------------------------------------------------------
// x [8][128][64][64] f32  ->  xTp [8][68][68][128] bf16 (2-px zero halo)
// one block per (b,h) row; LDS transpose for coalesced read AND write
__global__ __launch_bounds__(256) void k_xpad(const float* __restrict__ x,
                                              __hip_bfloat16* __restrict__ xTp) {
    int bh = blockIdx.x; int b = bh >> 6, h = bh & 63;
    __shared__ __hip_bfloat16 tile[64][130];   // [w][ci], pad->stride 65 dwords (conflict-free)
    int t = threadIdx.x;
#pragma unroll
    for (int i = 0; i < 32; ++i) {
        int e = (i << 8) + t; int w = e & 63; int ci = e >> 6;
        tile[w][ci] = __float2bfloat16(x[(((size_t)(b*128 + ci))*64 + h)*64 + w]);
    }
    __syncthreads();
    __hip_bfloat16* dst = xTp + ((size_t)((b*68 + h + 2)*68 + 2))*128;
#pragma unroll
    for (int i = 0; i < 32; ++i) {
        int e = (i << 8) + t; int ci = e & 127; int w = e >> 7;
        dst[w*128 + ci] = tile[w][ci];
    }
}

// ---------------------------------------------------------------------------
// w_mid [128][16][128][3][3] f32 -> wB2 [p][kt(36)][n(1024)][kk(32)] bf16
// n = c_local*16 + m (c = 2*c_local + p), k = kt*32+kk = tap*128 + ci
__global__ void k_wrepack(const float* __restrict__ w_mid,
                          __hip_bfloat16* __restrict__ wB2) {
    int idx = blockIdx.x * 256 + threadIdx.x;
    if (idx >= WB2_ELEMS) return;
    int kk  = idx & 31;
    int n   = (idx >> 5) & 1023;
    int rem = idx >> 15;             // p*36 + kt  (0..71)
    int kt = rem % 36, p = rem / 36;
    int c = ((n >> 4) << 1) + p, m = n & 15;
    int k = (kt << 5) + kk;
    int tap = k >> 7, ci = k & 127;
    wB2[idx] = __float2bfloat16(w_mid[((size_t)((c*16 + m)*128 + ci))*9 + tap]);
}

// ---------------------------------------------------------------------------
// Main implicit-GEMM conv. Tile: 128 spatial x 128 (c_local,m) cols, BK=32.
// 4 waves in 2x2. Writes pre-BN y[b][c][h][w] (f32) into d_out.
__global__ __launch_bounds__(256) void k_conv(
    const __hip_bfloat16* __restrict__ xTp,
    const __hip_bfloat16* __restrict__ wB2,
    const float* __restrict__ w_pt,
    const float* __restrict__ b_pt,
    float* __restrict__ y) {
    __shared__ __hip_bfloat16 Alds[128*32];   // [spatial row][k] 8 KB
    __shared__ __hip_bfloat16 Blds[128*32];   // [n][k]          8 KB

    const int bid = blockIdx.x;
    const int mt = bid & 255;          // 256 M tiles of 128 spatial
    const int nt = (bid >> 8) & 7;     // 8 N tiles of 128 within parity
    const int p  = bid >> 11;          // parity: 0 -> dil 1, 1 -> dil 2
    const int dil = 1 + p;

    const int t = threadIdx.x;
    const int lane = t & 63;
    const int wave = t >> 6;
    const int wm = wave >> 1, wn = wave & 1;

    const int rsub = t >> 2;           // staging row within 64-row pass
    const int ksub = (t & 3) << 3;     // k element offset 0/8/16/24

    int sb[2], sh[2], sw[2];
#pragma unroll
    for (int pass = 0; pass < 2; ++pass) {
        int s = mt*128 + pass*64 + rsub;
        sb[pass] = s >> 12; sh[pass] = (s >> 6) & 63; sw[pass] = s & 63;
    }
    const __hip_bfloat16* bsrc =
        wB2 + ((size_t)(p*36)*1024 + nt*128 + rsub)*32 + ksub;

    f32x4 acc[4][4];
#pragma unroll
    for (int i = 0; i < 4; ++i)
#pragma unroll
        for (int j = 0; j < 4; ++j) acc[i][j] = (f32x4){0.f, 0.f, 0.f, 0.f};

    const int lm = lane & 15;
    const int lg = lane >> 4;
    int aoff[4], boff[4];
#pragma unroll
    for (int i = 0; i < 4; ++i) {
        aoff[i] = (wm*64 + i*16 + lm)*32 + lg*8;
        boff[i] = (wn*64 + i*16 + lm)*32 + lg*8;
    }

    for (int kt = 0; kt < 36; ++kt) {
        int tap = kt >> 2;
        int ci0 = (kt & 3) << 5;
        int kh = tap / 3 - 1, kw = tap % 3 - 1;   // -1..1
#pragma unroll
        for (int pass = 0; pass < 2; ++pass) {
            int hh = sh[pass] + 2 + kh*dil;
            int ww = sw[pass] + 2 + kw*dil;
            const __hip_bfloat16* asrc =
                xTp + ((size_t)((sb[pass]*68 + hh)*68 + ww))*128 + ci0 + ksub;
            gload_lds16(asrc, (char*)Alds + pass*4096 + t*16);
            gload_lds16(bsrc + (size_t)kt*32768 + pass*2048,
                        (char*)Blds + pass*4096 + t*16);
        }
        __syncthreads();
        short8 af[4], bf[4];
#pragma unroll
        for (int i = 0; i < 4; ++i) af[i] = *(const short8*)(Alds + aoff[i]);
#pragma unroll
        for (int i = 0; i < 4; ++i) bf[i] = *(const short8*)(Blds + boff[i]);
#pragma unroll
        for (int i = 0; i < 4; ++i)
#pragma unroll
            for (int j = 0; j < 4; ++j)
                acc[i][j] = __builtin_amdgcn_mfma_f32_16x16x32_bf16(
                    af[i], bf[j], acc[i][j], 0, 0, 0);
        __syncthreads();
    }

    // epilogue: leaky -> *w_pt -> reduce over m (16 lanes) -> +b_pt -> y
#pragma unroll
    for (int j = 0; j < 4; ++j) {
        int n_g = nt*128 + wn*64 + j*16 + lm;
        int c = ((n_g >> 4) << 1) + p;     // uniform across the 16-lane group
        float wp = w_pt[c*16 + lm];        // m == lm
        float bp = b_pt[c];
#pragma unroll
        for (int i = 0; i < 4; ++i) {
#pragma unroll
            for (int r = 0; r < 4; ++r) {
                float v = acc[i][j][r];
                v = v >= 0.f ? v : 0.1f*v;
                v *= wp;
                v += __shfl_xor(v, 1);
                v += __shfl_xor(v, 2);
                v += __shfl_xor(v, 4);
                v += __shfl_xor(v, 8);
                if (lm == 0) {
                    int s = mt*128 + wm*64 + i*16 + lg*4 + r;
                    int b = s >> 12, hw = s & 4095;
                    y[(size_t)(b*128 + c)*4096 + hw] = v + bp;
                }
            }
        }
    }
}

// ---------------------------------------------------------------------------
// per-channel mean/var -> (scale, shift); one block per channel, deterministic
__global__ __launch_bounds__(256) void k_bn_stats(const float* __restrict__ y,
                                                  const float* __restrict__ gamma,
                                                  const float* __restrict__ beta,
                                                  float2* __restrict__ stats) {
    int c = blockIdx.x, t = threadIdx.x;
    float s = 0.f, s2 = 0.f;
    for (int b = 0; b < 8; ++b) {
        const float* base = y + (size_t)(b*128 + c)*4096;
        for (int i = t; i < 4096; i += 256) {
            float v = base[i]; s += v; s2 += v*v;
        }
    }
#pragma unroll
    for (int o = 32; o; o >>= 1) { s += __shfl_down(s, o); s2 += __shfl_down(s2, o); }
    __shared__ float ss[4], ss2[4];
    if ((t & 63) == 0) { ss[t >> 6] = s; ss2[t >> 6] = s2; }
    __syncthreads();
    if (t == 0) {
        s = ss[0] + ss[1] + ss[2] + ss[3];
        s2 = ss2[0] + ss2[1] + ss2[2] + ss2[3];
        float mean = s * (1.f/32768.f);
        float var  = s2 * (1.f/32768.f) - mean*mean;
        float scale = gamma[c] * rsqrtf(var + EPSV);
        stats[c] = make_float2(scale, beta[c] - mean*scale);
    }
}

// in-place BN + ReLU, float4 vectorized (exact grid: 1,048,576 float4s)
__global__ void k_bn_apply(float* __restrict__ y, const float2* __restrict__ stats) {
    int idx = blockIdx.x * 256 + threadIdx.x;
    int c = (idx >> 10) & 127;         // element index = idx*4; c = (e>>12)&127
    float2 sc = stats[c];
    float4* y4 = (float4*)y;
    float4 v = y4[idx];
    v.x = fmaxf(v.x*sc.x + sc.y, 0.f);
    v.y = fmaxf(v.y*sc.x + sc.y, 0.f);
    v.z = fmaxf(v.z*sc.x + sc.y, 0.f);
    v.w = fmaxf(v.w*sc.x + sc.y, 0.f);
    y4[idx] = v;
}

// ---------------------------------------------------------------------------
extern "C" void kernel_launch(void* const* d_in, const int* in_sizes, int n_in,
                              void* d_out, int out_size, void* d_ws, size_t ws_size,
                              hipStream_t stream) {
    const float* x     = (const float*)d_in[0];
    const float* w_mid = (const float*)d_in[1];
    const float* w_pt  = (const float*)d_in[2];
    const float* b_pt  = (const float*)d_in[3];
    const float* gamma = (const float*)d_in[4];
    const float* beta  = (const float*)d_in[5];
    float* y = (float*)d_out;

    __hip_bfloat16* xTp = (__hip_bfloat16*)d_ws;
    __hip_bfloat16* wB2 = (__hip_bfloat16*)((char*)d_ws + XTP_BYTES);
    float2* stats       = (float2*)((char*)d_ws + STATS_OFF);
    // requires ws_size >= ~14.2 MB

    hipMemsetAsync(d_ws, 0, XTP_BYTES, stream);                 // zero halo
    k_xpad<<<512, 256, 0, stream>>>(x, xTp);
    k_wrepack<<<(WB2_ELEMS + 255) / 256, 256, 0, stream>>>(w_mid, wB2);
    k_conv<<<4096, 256, 0, stream>>>(xTp, wB2, w_pt, b_pt, y);
    k_bn_stats<<<128, 256, 0, stream>>>(y, gamma, beta, stats);
    k_bn_apply<<<4096, 256, 0, stream>>>(y, stats);
}

// Round 2
// 344.448 us; speedup vs baseline: 1.0013x; 1.0013x over previous
//
#include <hip/hip_runtime.h>
#include <hip/hip_bf16.h>

// Sizes
#define NB   8
#define CIN  128
#define HH_  64
#define WW_  64
#define COUT 128
#define MIDC 16
#define EPSV 1e-5f

// workspace layout
#define XTP_ELEMS (8*68*68*128)            // padded channels-last x, bf16
#define XTP_BYTES ((size_t)XTP_ELEMS*2)    // 9,469,952
#define WB2_ELEMS (2*36*1024*32)           // repacked weights, bf16
#define WB2_BYTES ((size_t)WB2_ELEMS*2)    // 4,718,592
#define STATS_OFF (XTP_BYTES + WB2_BYTES)  // 128 float2

typedef __attribute__((ext_vector_type(8))) short short8;
typedef __attribute__((ext_vector_type(4))) float f32x4;

__device__ __forceinline__ void gload_lds16(const void* g, void* l) {
    __builtin_amdgcn_global_load_lds(
        (const __attribute__((address_space(1))) void*)g,
        (__attribute__((address_space(3))) void*)l, 16, 0, 0);
}

// ---------------------------------------------------------------------------
// x [8][128][64][64] f32  ->  xTp [8][68][68][128] bf16 (2-px zero halo)
__global__ __launch_bounds__(256) void k_xpad(const float* __restrict__ x,
                                              __hip_bfloat16* __restrict__ xTp) {
    int bh = blockIdx.x; int b = bh >> 6, h = bh & 63;
    __shared__ __hip_bfloat16 tile[64][130];
    int t = threadIdx.x;
#pragma unroll
    for (int i = 0; i < 32; ++i) {
        int e = (i << 8) + t; int w = e & 63; int ci = e >> 6;
        tile[w][ci] = __float2bfloat16(x[(((size_t)(b*128 + ci))*64 + h)*64 + w]);
    }
    __syncthreads();
    __hip_bfloat16* dst = xTp + ((size_t)((b*68 + h + 2)*68 + 2))*128;
#pragma unroll
    for (int i = 0; i < 32; ++i) {
        int e = (i << 8) + t; int ci = e & 127; int w = e >> 7;
        dst[w*128 + ci] = tile[w][ci];
    }
}

// ---------------------------------------------------------------------------
// w_mid [128][16][128][3][3] f32 -> wB2 [p][kt(36)][n(1024)][kk(32)] bf16
// n = c_local*16 + m (c = 2*c_local + p), k = kt*32+kk = tap*128 + ci
__global__ void k_wrepack(const float* __restrict__ w_mid,
                          __hip_bfloat16* __restrict__ wB2) {
    int idx = blockIdx.x * 256 + threadIdx.x;
    if (idx >= WB2_ELEMS) return;
    int kk  = idx & 31;
    int n   = (idx >> 5) & 1023;
    int rem = idx >> 15;             // p*36 + kt  (0..71)
    int kt = rem % 36, p = rem / 36;
    int c = ((n >> 4) << 1) + p, m = n & 15;
    int k = (kt << 5) + kk;
    int tap = k >> 7, ci = k & 127;
    wB2[idx] = __float2bfloat16(w_mid[((size_t)((c*16 + m)*128 + ci))*9 + tap]);
}

// ---------------------------------------------------------------------------
// Main implicit-GEMM conv. Tile: 128 spatial x 128 (c_local,m) cols, BK=32.
// LDS rows [128][32] bf16; 16B slots XOR-swizzled: phys = log ^ ((row>>1)&3),
// applied on the GLOBAL source (linear LDS dest for global_load_lds) and on
// the ds_read offsets — 2-way bank access (free) instead of 8-way.
__global__ __launch_bounds__(256) void k_conv(
    const __hip_bfloat16* __restrict__ xTp,
    const __hip_bfloat16* __restrict__ wB2,
    const float* __restrict__ w_pt,
    const float* __restrict__ b_pt,
    float* __restrict__ y) {
    __shared__ __hip_bfloat16 Alds[128*32];   // 8 KB
    __shared__ __hip_bfloat16 Blds[128*32];   // 8 KB

    const int bid = blockIdx.x;
    const int mt = bid & 255;          // 256 M tiles of 128 spatial
    const int nt = (bid >> 8) & 7;     // 8 N tiles of 128 within parity
    const int p  = bid >> 11;          // parity: 0 -> dil 1, 1 -> dil 2
    const int dil = 1 + p;

    const int t = threadIdx.x;
    const int lane = t & 63;
    const int wave = t >> 6;
    const int wm = wave >> 1, wn = wave & 1;

    const int rsub = t >> 2;                              // staging row in 64-row pass
    const int ksub = (((t & 3) ^ ((t >> 3) & 3)) << 3);   // swizzled logical slot (elems)

    // A source base pointers (tap center, k-chunk 0) per 64-row pass
    const __hip_bfloat16* abase[2];
#pragma unroll
    for (int pass = 0; pass < 2; ++pass) {
        int s = mt*128 + pass*64 + rsub;
        int b = s >> 12, h = (s >> 6) & 63, w = s & 63;
        abase[pass] = xTp + ((size_t)((b*68 + h + 2)*68 + (w + 2)))*128 + ksub;
    }
    const __hip_bfloat16* bsrc =
        wB2 + ((size_t)(p*36)*1024 + nt*128 + rsub)*32 + ksub;

    f32x4 acc[4][4];
#pragma unroll
    for (int i = 0; i < 4; ++i)
#pragma unroll
        for (int j = 0; j < 4; ++j) acc[i][j] = (f32x4){0.f, 0.f, 0.f, 0.f};

    const int lm = lane & 15;
    const int lg = lane >> 4;
    const int sslot = (lg ^ ((lm >> 1) & 3)) << 3;   // swizzled read slot (elems)
    int aoff[4], boff[4];
#pragma unroll
    for (int i = 0; i < 4; ++i) {
        aoff[i] = (wm*64 + i*16 + lm)*32 + sslot;
        boff[i] = (wn*64 + i*16 + lm)*32 + sslot;
    }

    const int drow = dil*68*128;   // A byte-row delta per kh (in elems)
    const int dcol = dil*128;
    for (int kh = -1; kh <= 1; ++kh) {
        for (int kw = -1; kw <= 1; ++kw) {
            const __hip_bfloat16* a0 = abase[0] + kh*drow + kw*dcol;
            const __hip_bfloat16* a1 = abase[1] + kh*drow + kw*dcol;
#pragma unroll
            for (int kc = 0; kc < 4; ++kc) {
                gload_lds16(a0 + kc*32, (char*)Alds + t*16);
                gload_lds16(a1 + kc*32, (char*)Alds + 4096 + t*16);
                gload_lds16(bsrc,        (char*)Blds + t*16);
                gload_lds16(bsrc + 2048, (char*)Blds + 4096 + t*16);
                bsrc += 32768;
                __syncthreads();
                short8 af[4], bf[4];
#pragma unroll
                for (int i = 0; i < 4; ++i) af[i] = *(const short8*)(Alds + aoff[i]);
#pragma unroll
                for (int i = 0; i < 4; ++i) bf[i] = *(const short8*)(Blds + boff[i]);
#pragma unroll
                for (int i = 0; i < 4; ++i)
#pragma unroll
                    for (int j = 0; j < 4; ++j)
                        acc[i][j] = __builtin_amdgcn_mfma_f32_16x16x32_bf16(
                            af[i], bf[j], acc[i][j], 0, 0, 0);
                __syncthreads();
            }
        }
    }

    // epilogue: leaky -> *w_pt -> reduce over m (16 lanes) -> +b_pt -> y
#pragma unroll
    for (int j = 0; j < 4; ++j) {
        int n_g = nt*128 + wn*64 + j*16 + lm;
        int c = ((n_g >> 4) << 1) + p;     // uniform across the 16-lane group
        float wp = w_pt[c*16 + lm];        // m == lm
        float bp = b_pt[c];
#pragma unroll
        for (int i = 0; i < 4; ++i) {
#pragma unroll
            for (int r = 0; r < 4; ++r) {
                float v = acc[i][j][r];
                v = v >= 0.f ? v : 0.1f*v;
                v *= wp;
                v += __shfl_xor(v, 1);
                v += __shfl_xor(v, 2);
                v += __shfl_xor(v, 4);
                v += __shfl_xor(v, 8);
                if (lm == 0) {
                    int s = mt*128 + wm*64 + i*16 + lg*4 + r;
                    int b = s >> 12, hw = s & 4095;
                    y[(size_t)(b*128 + c)*4096 + hw] = v + bp;
                }
            }
        }
    }
}

// ---------------------------------------------------------------------------
// per-channel mean/var -> (scale, shift); one block per channel, deterministic
__global__ __launch_bounds__(256) void k_bn_stats(const float* __restrict__ y,
                                                  const float* __restrict__ gamma,
                                                  const float* __restrict__ beta,
                                                  float2* __restrict__ stats) {
    int c = blockIdx.x, t = threadIdx.x;
    float s = 0.f, s2 = 0.f;
    for (int b = 0; b < 8; ++b) {
        const float* base = y + (size_t)(b*128 + c)*4096;
        for (int i = t; i < 4096; i += 256) {
            float v = base[i]; s += v; s2 += v*v;
        }
    }
#pragma unroll
    for (int o = 32; o; o >>= 1) { s += __shfl_down(s, o); s2 += __shfl_down(s2, o); }
    __shared__ float ss[4], ss2[4];
    if ((t & 63) == 0) { ss[t >> 6] = s; ss2[t >> 6] = s2; }
    __syncthreads();
    if (t == 0) {
        s = ss[0] + ss[1] + ss[2] + ss[3];
        s2 = ss2[0] + ss2[1] + ss2[2] + ss2[3];
        float mean = s * (1.f/32768.f);
        float var  = s2 * (1.f/32768.f) - mean*mean;
        float scale = gamma[c] * rsqrtf(var + EPSV);
        stats[c] = make_float2(scale, beta[c] - mean*scale);
    }
}

// in-place BN + ReLU, float4 vectorized (exact grid: 1,048,576 float4s)
__global__ void k_bn_apply(float* __restrict__ y, const float2* __restrict__ stats) {
    int idx = blockIdx.x * 256 + threadIdx.x;
    int c = (idx >> 10) & 127;
    float2 sc = stats[c];
    float4* y4 = (float4*)y;
    float4 v = y4[idx];
    v.x = fmaxf(v.x*sc.x + sc.y, 0.f);
    v.y = fmaxf(v.y*sc.x + sc.y, 0.f);
    v.z = fmaxf(v.z*sc.x + sc.y, 0.f);
    v.w = fmaxf(v.w*sc.x + sc.y, 0.f);
    y4[idx] = v;
}

// ---------------------------------------------------------------------------
extern "C" void kernel_launch(void* const* d_in, const int* in_sizes, int n_in,
                              void* d_out, int out_size, void* d_ws, size_t ws_size,
                              hipStream_t stream) {
    const float* x     = (const float*)d_in[0];
    const float* w_mid = (const float*)d_in[1];
    const float* w_pt  = (const float*)d_in[2];
    const float* b_pt  = (const float*)d_in[3];
    const float* gamma = (const float*)d_in[4];
    const float* beta  = (const float*)d_in[5];
    float* y = (float*)d_out;

    __hip_bfloat16* xTp = (__hip_bfloat16*)d_ws;
    __hip_bfloat16* wB2 = (__hip_bfloat16*)((char*)d_ws + XTP_BYTES);
    float2* stats       = (float2*)((char*)d_ws + STATS_OFF);

    hipMemsetAsync(d_ws, 0, XTP_BYTES, stream);                 // zero halo
    k_xpad<<<512, 256, 0, stream>>>(x, xTp);
    k_wrepack<<<(WB2_ELEMS + 255) / 256, 256, 0, stream>>>(w_mid, wB2);
    k_conv<<<4096, 256, 0, stream>>>(xTp, wB2, w_pt, b_pt, y);
    k_bn_stats<<<128, 256, 0, stream>>>(y, gamma, beta, stats);
    k_bn_apply<<<4096, 256, 0, stream>>>(y, stats);
}

// Round 3
// 277.986 us; speedup vs baseline: 1.2407x; 1.2391x over previous
//
#include <hip/hip_runtime.h>
#include <hip/hip_bf16.h>

// Sizes
#define NB   8
#define CIN  128
#define EPSV 1e-5f

// workspace layout
#define XTP_ELEMS (8*68*68*128)            // padded channels-last x, bf16
#define XTP_BYTES ((size_t)XTP_ELEMS*2)    // 9,469,952
#define WB2_ELEMS (2*36*1024*32)           // repacked weights, bf16
#define WB2_BYTES ((size_t)WB2_ELEMS*2)    // 4,718,592
#define STATS_OFF (XTP_BYTES + WB2_BYTES)  // 1024 float2 partials

typedef __attribute__((ext_vector_type(8))) short short8;
typedef __attribute__((ext_vector_type(4))) float f32x4;

__device__ __forceinline__ void gload_lds16(const void* g, void* l) {
    __builtin_amdgcn_global_load_lds(
        (const __attribute__((address_space(1))) void*)g,
        (__attribute__((address_space(3))) void*)l, 16, 0, 0);
}

// ---------------------------------------------------------------------------
// x [8][128][64][64] f32  ->  xTp [8][68][68][128] bf16 (2-px zero halo)
__global__ __launch_bounds__(256) void k_xpad(const float* __restrict__ x,
                                              __hip_bfloat16* __restrict__ xTp) {
    int bh = blockIdx.x; int b = bh >> 6, h = bh & 63;
    __shared__ __hip_bfloat16 tile[64][130];
    int t = threadIdx.x;
#pragma unroll
    for (int i = 0; i < 32; ++i) {
        int e = (i << 8) + t; int w = e & 63; int ci = e >> 6;
        tile[w][ci] = __float2bfloat16(x[(((size_t)(b*128 + ci))*64 + h)*64 + w]);
    }
    __syncthreads();
    __hip_bfloat16* dst = xTp + ((size_t)((b*68 + h + 2)*68 + 2))*128;
#pragma unroll
    for (int i = 0; i < 32; ++i) {
        int e = (i << 8) + t; int ci = e & 127; int w = e >> 7;
        dst[w*128 + ci] = tile[w][ci];
    }
}

// ---------------------------------------------------------------------------
// w_mid [128][16][128][3][3] f32 -> wB2 [p][kt(36)][n(1024)][kk(32)] bf16
__global__ void k_wrepack(const float* __restrict__ w_mid,
                          __hip_bfloat16* __restrict__ wB2) {
    int idx = blockIdx.x * 256 + threadIdx.x;
    if (idx >= WB2_ELEMS) return;
    int kk  = idx & 31;
    int n   = (idx >> 5) & 1023;
    int rem = idx >> 15;             // p*36 + kt
    int kt = rem % 36, p = rem / 36;
    int c = ((n >> 4) << 1) + p, m = n & 15;
    int k = (kt << 5) + kk;
    int tap = k >> 7, ci = k & 127;
    wB2[idx] = __float2bfloat16(w_mid[((size_t)((c*16 + m)*128 + ci))*9 + tap]);
}

// ---------------------------------------------------------------------------
// Implicit-GEMM conv, 2-phase pipelined. 128 spatial x 128 cols, BK=32.
// A: global_load_lds -> swizzled LDS (double-buffered). B: global->reg direct
// (perfectly coalesced 1KB/wave, L2-resident), reg double-buffered.
// One barrier per K-step; loads for t+1 hide under compute of t.
__global__ __launch_bounds__(256, 3) void k_conv(
    const __hip_bfloat16* __restrict__ xTp,
    const __hip_bfloat16* __restrict__ wB2,
    const float* __restrict__ w_pt,
    const float* __restrict__ b_pt,
    float* __restrict__ y) {
    __shared__ __hip_bfloat16 Alds[2*128*32];   // 2 x 8 KB

    // XCD-chunked swizzle (nwg=4096, divisible by 8): xcd = hwbid%8 owns a
    // contiguous logical chunk of 512 blocks; mt-major order so each chunk
    // shares A panels and the full (small) B across its L2.
    const int lb = (blockIdx.x & 7) * 512 + (blockIdx.x >> 3);
    const int p  = lb & 1;             // parity: dil 1 / dil 2
    const int nt = (lb >> 1) & 7;      // N tile within parity
    const int mt = lb >> 4;            // spatial tile (0..255)
    const int dil = 1 + p;

    const int t = threadIdx.x;
    const int lane = t & 63;
    const int wave = t >> 6;
    const int wm = wave >> 1, wn = wave & 1;

    const int rsub = t >> 2;                              // staging row
    const int ksub = (((t & 3) ^ ((t >> 3) & 3)) << 3);   // swizzled slot (elems)

    // A source base pointers (tap center, k-chunk 0) per 64-row pass
    const __hip_bfloat16* abase0;
    const __hip_bfloat16* abase1;
    {
        int s0 = mt*128 + rsub;
        int s1 = s0 + 64;
        abase0 = xTp + ((size_t)(((s0>>12)*68 + ((s0>>6)&63) + 2)*68 + (s0&63) + 2))*128 + ksub;
        abase1 = xTp + ((size_t)(((s1>>12)*68 + ((s1>>6)&63) + 2)*68 + (s1&63) + 2))*128 + ksub;
    }

    const int lm = lane & 15;
    const int lg = lane >> 4;
    // B fragment base: cols nt*128 + wn*64 + j*16 + lm, k-slot lg
    const __hip_bfloat16* bglob =
        wB2 + ((size_t)(p*36)*1024 + nt*128 + wn*64 + lm)*32 + lg*8;

    f32x4 acc[4][4];
#pragma unroll
    for (int i = 0; i < 4; ++i)
#pragma unroll
        for (int j = 0; j < 4; ++j) acc[i][j] = (f32x4){0.f, 0.f, 0.f, 0.f};

    const int sslot = (lg ^ ((lm >> 1) & 3)) << 3;   // swizzled read slot (elems)
    int aoff[4];
#pragma unroll
    for (int i = 0; i < 4; ++i)
        aoff[i] = (wm*64 + i*16 + lm)*32 + sslot;

    // ---- prologue: stage kt=0 (A->LDS buf0, B->reg set0) ----
    short8 breg[2][4];
    {
        // tap 0: kh=-1, kw=-1, ci0=0
        int toff = dil * 128 * (-69);
        gload_lds16(abase0 + toff, (char*)Alds + t*16);
        gload_lds16(abase1 + toff, (char*)Alds + 4096 + t*16);
#pragma unroll
        for (int j = 0; j < 4; ++j)
            breg[0][j] = *(const short8*)(bglob + j*512);
    }
    __syncthreads();

    // ---- main loop: fully unrolled so dbuf indices are static ----
#pragma unroll
    for (int kt = 0; kt < 36; ++kt) {
        const int cur = kt & 1;
        if (kt < 35) {
            const int k2 = kt + 1;
            const int tap = k2 >> 2;
            const int ci0 = (k2 & 3) << 5;
            const int kh = tap/3 - 1, kw = tap%3 - 1;
            const int toff = dil * (128 * (kh*68 + kw)) + ci0;
            gload_lds16(abase0 + toff, (char*)Alds + (k2&1)*8192 + t*16);
            gload_lds16(abase1 + toff, (char*)Alds + (k2&1)*8192 + 4096 + t*16);
            const __hip_bfloat16* bp = bglob + (size_t)k2*32768;
#pragma unroll
            for (int j = 0; j < 4; ++j)
                breg[k2 & 1][j] = *(const short8*)(bp + j*512);
        }
        short8 af[4];
#pragma unroll
        for (int i = 0; i < 4; ++i)
            af[i] = *(const short8*)(Alds + cur*4096 + aoff[i]);
        __builtin_amdgcn_s_setprio(1);
#pragma unroll
        for (int i = 0; i < 4; ++i)
#pragma unroll
            for (int j = 0; j < 4; ++j)
                acc[i][j] = __builtin_amdgcn_mfma_f32_16x16x32_bf16(
                    af[i], breg[cur][j], acc[i][j], 0, 0, 0);
        __builtin_amdgcn_s_setprio(0);
        __syncthreads();
    }

    // epilogue: leaky -> *w_pt -> reduce over m (16 lanes) -> +b_pt -> y
#pragma unroll
    for (int j = 0; j < 4; ++j) {
        int n_g = nt*128 + wn*64 + j*16 + lm;
        int c = ((n_g >> 4) << 1) + p;     // uniform across the 16-lane group
        float wp = w_pt[c*16 + lm];        // m == lm
        float bp = b_pt[c];
#pragma unroll
        for (int i = 0; i < 4; ++i) {
#pragma unroll
            for (int r = 0; r < 4; ++r) {
                float v = acc[i][j][r];
                v = v >= 0.f ? v : 0.1f*v;
                v *= wp;
                v += __shfl_xor(v, 1);
                v += __shfl_xor(v, 2);
                v += __shfl_xor(v, 4);
                v += __shfl_xor(v, 8);
                if (lm == 0) {
                    int s = mt*128 + wm*64 + i*16 + lg*4 + r;
                    int b = s >> 12, hw = s & 4095;
                    y[(size_t)(b*128 + c)*4096 + hw] = v + bp;
                }
            }
        }
    }
}

// ---------------------------------------------------------------------------
// per-(b,c)-plane partial sums (float4 loads, no atomics, deterministic)
__global__ __launch_bounds__(256) void k_ystat(const float* __restrict__ y,
                                               float2* __restrict__ partials) {
    int P = blockIdx.x;                 // plane = b*128 + c
    const float4* base = (const float4*)(y + (size_t)P*4096);
    int t = threadIdx.x;
    float s = 0.f, s2 = 0.f;
#pragma unroll
    for (int i = 0; i < 4; ++i) {
        float4 v = base[t + i*256];
        s  += v.x + v.y + v.z + v.w;
        s2 += v.x*v.x + v.y*v.y + v.z*v.z + v.w*v.w;
    }
#pragma unroll
    for (int o = 32; o; o >>= 1) { s += __shfl_down(s, o); s2 += __shfl_down(s2, o); }
    __shared__ float ss[4], ss2[4];
    if ((t & 63) == 0) { ss[t >> 6] = s; ss2[t >> 6] = s2; }
    __syncthreads();
    if (t == 0)
        partials[P] = make_float2(ss[0]+ss[1]+ss[2]+ss[3], ss2[0]+ss2[1]+ss2[2]+ss2[3]);
}

// BN finalize + apply + ReLU. Block covers 256 float4 = quarter of one plane.
__global__ __launch_bounds__(256) void k_bn_apply(float* __restrict__ y,
                                                  const float2* __restrict__ partials,
                                                  const float* __restrict__ gamma,
                                                  const float* __restrict__ beta) {
    int bid = blockIdx.x;
    int c = (bid >> 2) & 127;
    float s = 0.f, s2 = 0.f;
#pragma unroll
    for (int b = 0; b < 8; ++b) {
        float2 pr = partials[b*128 + c];
        s += pr.x; s2 += pr.y;
    }
    float mean = s * (1.f/32768.f);
    float var  = s2 * (1.f/32768.f) - mean*mean;
    float scale = gamma[c] * rsqrtf(var + EPSV);
    float shift = beta[c] - mean*scale;
    float4* y4 = (float4*)y;
    int idx = bid*256 + threadIdx.x;
    float4 v = y4[idx];
    v.x = fmaxf(v.x*scale + shift, 0.f);
    v.y = fmaxf(v.y*scale + shift, 0.f);
    v.z = fmaxf(v.z*scale + shift, 0.f);
    v.w = fmaxf(v.w*scale + shift, 0.f);
    y4[idx] = v;
}

// ---------------------------------------------------------------------------
extern "C" void kernel_launch(void* const* d_in, const int* in_sizes, int n_in,
                              void* d_out, int out_size, void* d_ws, size_t ws_size,
                              hipStream_t stream) {
    const float* x     = (const float*)d_in[0];
    const float* w_mid = (const float*)d_in[1];
    const float* w_pt  = (const float*)d_in[2];
    const float* b_pt  = (const float*)d_in[3];
    const float* gamma = (const float*)d_in[4];
    const float* beta  = (const float*)d_in[5];
    float* y = (float*)d_out;

    __hip_bfloat16* xTp = (__hip_bfloat16*)d_ws;
    __hip_bfloat16* wB2 = (__hip_bfloat16*)((char*)d_ws + XTP_BYTES);
    float2* partials    = (float2*)((char*)d_ws + STATS_OFF);

    hipMemsetAsync(d_ws, 0, XTP_BYTES, stream);                 // zero halo
    k_xpad<<<512, 256, 0, stream>>>(x, xTp);
    k_wrepack<<<(WB2_ELEMS + 255) / 256, 256, 0, stream>>>(w_mid, wB2);
    k_conv<<<4096, 256, 0, stream>>>(xTp, wB2, w_pt, b_pt, y);
    k_ystat<<<1024, 256, 0, stream>>>(y, partials);
    k_bn_apply<<<4096, 256, 0, stream>>>(y, partials, gamma, beta);
}